// Round 1
// baseline (74.425 us; speedup 1.0000x reference)
//
#include <hip/hip_runtime.h>

#define CCH 3
#define KK 16
#define HW (1024 * 1024)

__global__ __launch_bounds__(256) void pixelwise_kernel(
    const float* __restrict__ x,
    const float* __restrict__ M,
    const float* __restrict__ p_a,
    const float* __restrict__ p_t,
    const float* __restrict__ bias_c,
    const float* __restrict__ bias,
    float* __restrict__ out)
{
    // Uniform parameters — all addresses wave-uniform, compiler scalarizes (s_load).
    float rs[CCH];
#pragma unroll
    for (int c = 0; c < CCH; ++c)
        rs[c] = M[c * 3 + 0] + M[c * 3 + 1] + M[c * 3 + 2];

    // relu(z) = (z + |z|) * 0.5  =>
    //   sum_k pa_k * relu(s + bb_k) = A*s + B + sum_k h_k * |s + bb_k|
    // with h_k = pa_k/2 (uniform), bb_k = bias_c - p_t (uniform),
    //      A = sum h_k, B = sum h_k*bb_k  (uniform, folded once).
    // |z| is a free VOP3 src modifier on the consuming v_fma -> 2 VALU ops
    // per hinge term instead of 3 (add+max+fma).
    float h[CCH][KK];   // pa/2
    float bb[CCH][KK];  // bias_c - p_t
    float A[CCH];
    float binit = bias[0];
#pragma unroll
    for (int c = 0; c < CCH; ++c) {
        float Ac = 0.0f, Bc = 0.0f;
#pragma unroll
        for (int k = 0; k < KK; ++k) {
            const float hk = 0.5f * p_a[c * KK + k];
            const float bk = bias_c[c] - p_t[c * KK + k];
            h[c][k]  = hk;
            bb[c][k] = bk;
            Ac += hk;
            Bc = fmaf(hk, bk, Bc);
        }
        A[c] = Ac;
        binit += Bc;   // all-uniform offset folds into accumulator init
    }

    const int idx  = blockIdx.x * blockDim.x + threadIdx.x;
    const int base = idx * 4;
    if (base >= HW) return;

    const float4 x0 = *(const float4*)(x + 0 * HW + base);
    const float4 x1 = *(const float4*)(x + 1 * HW + base);
    const float4 x2 = *(const float4*)(x + 2 * HW + base);

    float a0 = binit, a1 = binit, a2 = binit, a3 = binit;

#pragma unroll
    for (int c = 0; c < CCH; ++c) {
        const float4 xv = (c == 0) ? x0 : (c == 1) ? x1 : x2;
        const float s0 = xv.x * rs[c];
        const float s1 = xv.y * rs[c];
        const float s2 = xv.z * rs[c];
        const float s3 = xv.w * rs[c];

        // linear part: A*s
        a0 = fmaf(A[c], s0, a0);
        a1 = fmaf(A[c], s1, a1);
        a2 = fmaf(A[c], s2, a2);
        a3 = fmaf(A[c], s3, a3);

#pragma unroll
        for (int k = 0; k < KK; ++k) {
            const float z0 = s0 + bb[c][k];
            const float z1 = s1 + bb[c][k];
            const float z2 = s2 + bb[c][k];
            const float z3 = s3 + bb[c][k];
            a0 = fmaf(h[c][k], fabsf(z0), a0);
            a1 = fmaf(h[c][k], fabsf(z1), a1);
            a2 = fmaf(h[c][k], fabsf(z2), a2);
            a3 = fmaf(h[c][k], fabsf(z3), a3);
        }
    }

    *(float4*)(out + base) = make_float4(a0, a1, a2, a3);
}

extern "C" void kernel_launch(void* const* d_in, const int* in_sizes, int n_in,
                              void* d_out, int out_size, void* d_ws, size_t ws_size,
                              hipStream_t stream)
{
    const float* x      = (const float*)d_in[0];
    const float* M      = (const float*)d_in[1];
    const float* p_a    = (const float*)d_in[2];
    const float* p_t    = (const float*)d_in[3];
    const float* bias_c = (const float*)d_in[4];
    const float* bias   = (const float*)d_in[5];
    float* out = (float*)d_out;

    const int threads = 256;
    const int groups  = HW / 4;            // one float4 per thread
    const int blocks  = groups / threads;  // 1024 blocks = 4/CU, 16 waves/CU
    pixelwise_kernel<<<blocks, threads, 0, stream>>>(x, M, p_a, p_t, bias_c, bias, out);
}